// Round 9
// baseline (224.471 us; speedup 1.0000x reference)
//
#include <hip/hip_runtime.h>
#include <hip/hip_bf16.h>
#include <math.h>

#define D_MODEL 768
#define N_HEAD  12
#define SEQ     2048
#define BATCH   4
#define HD      64
#define BH      (BATCH*N_HEAD)

typedef __bf16 bf16;
typedef __bf16 bf16x4 __attribute__((ext_vector_type(4)));
typedef __bf16 bf16x8 __attribute__((ext_vector_type(8)));
typedef float  f32x4  __attribute__((ext_vector_type(4)));
typedef float  f32x16 __attribute__((ext_vector_type(16)));
typedef unsigned int u32;

__device__ __forceinline__ f32x4 mfma16(bf16x8 a, bf16x8 b, f32x4 c) {
    return __builtin_amdgcn_mfma_f32_16x16x32_bf16(a, b, c, 0, 0, 0);
}
__device__ __forceinline__ f32x16 mfma32(bf16x8 a, bf16x8 b, f32x16 c) {
    return __builtin_amdgcn_mfma_f32_32x32x16_bf16(a, b, c, 0, 0, 0);
}

// async global->LDS, 16B per lane; LDS dest = wave-uniform base + lane*16
__device__ __forceinline__ void gload16(const void* g, void* l) {
    __builtin_amdgcn_global_load_lds((const __attribute__((address_space(1))) u32*)g,
                                     (__attribute__((address_space(3))) u32*)l, 16, 0, 0);
}

// ---------------- prep kernels ----------------
__global__ void cvt_bf16(const float* __restrict__ in, bf16* __restrict__ out, int n) {
    int i = (blockIdx.x * blockDim.x + threadIdx.x) * 4;
    if (i < n) {
        float4 v = *(const float4*)(in + i);
        bf16x4 o;
        o[0] = (bf16)v.x; o[1] = (bf16)v.y; o[2] = (bf16)v.z; o[3] = (bf16)v.w;
        *(bf16x4*)(out + i) = o;
    }
}

// in [R][C] fp32 -> out [C][R] bf16, LDS-tiled 64x64 (R,C multiples of 64)
__global__ __launch_bounds__(256)
void transpose_cvt(const float* __restrict__ in, bf16* __restrict__ out, int R, int C) {
    __shared__ float tile[64][65];
    int tid = threadIdx.x;
    int tr = blockIdx.y * 64, tc = blockIdx.x * 64;
    int r0 = tid >> 4, c0 = (tid & 15) * 4;
    #pragma unroll
    for (int i = 0; i < 4; ++i) {
        float4 v = *(const float4*)&in[(long)(tr + r0 + i * 16) * C + tc + c0];
        tile[r0 + i * 16][c0 + 0] = v.x;
        tile[r0 + i * 16][c0 + 1] = v.y;
        tile[r0 + i * 16][c0 + 2] = v.z;
        tile[r0 + i * 16][c0 + 3] = v.w;
    }
    __syncthreads();
    int orr = (tid & 15) * 4;
    #pragma unroll
    for (int i = 0; i < 4; ++i) {
        int oc = (tid >> 4) + i * 16;
        bf16x4 o;
        #pragma unroll
        for (int j = 0; j < 4; ++j) o[j] = (bf16)tile[orr + j][oc];
        *(bf16x4*)&out[(long)(tc + oc) * R + tr + orr] = o;
    }
}

// ---------------- GEMM (m97 structure): C = A[M,K] * Bt[N,K]^T + bias ----------------
// MODE 0: QKV epilogue (q pre-scaled by 0.125*log2e; scatter q/k row-major, v transposed), MODE 1: fp32 out
template<int MODE>
__global__ __launch_bounds__(256)
void gemm_bt(const bf16* __restrict__ A, const bf16* __restrict__ Bt,
             const float* __restrict__ bias,
             bf16* __restrict__ qo, bf16* __restrict__ ko, bf16* __restrict__ vto,
             float* __restrict__ outf,
             int M, int N, int K) {
    __shared__ bf16 As[128 * 32];   // linear, row stride 32 el (64B)
    __shared__ bf16 Bs[128 * 32];
    int tid = threadIdx.x;
    int wave = tid >> 6, lane = tid & 63;
    int wr = wave >> 1, wc = wave & 1;
    int lq = lane >> 4, lc = lane & 15;
    int mbase = blockIdx.x * 128, nbase = blockIdx.y * 128;
    int srow = wave * 32 + (lane >> 2), scol = (lane & 3) * 8;
    const bf16* aS = A  + (long)(mbase + srow) * K + scol;
    const bf16* bS = Bt + (long)(nbase + srow) * K + scol;
    char* AsB = (char*)As + wave * 2048;
    char* BsB = (char*)Bs + wave * 2048;
    f32x4 acc[4][4] = {};
    for (int kt = 0; kt < K; kt += 32) {
        gload16(aS + kt,                AsB);
        gload16(aS + 16 * (long)K + kt, AsB + 1024);
        gload16(bS + kt,                BsB);
        gload16(bS + 16 * (long)K + kt, BsB + 1024);
        __syncthreads();
        bf16x8 af[4], bfr[4];
        #pragma unroll
        for (int mf = 0; mf < 4; ++mf)
            af[mf]  = *(const bf16x8*)((char*)As + (wr * 64 + mf * 16 + lc) * 64 + lq * 16);
        #pragma unroll
        for (int nf = 0; nf < 4; ++nf)
            bfr[nf] = *(const bf16x8*)((char*)Bs + (wc * 64 + nf * 16 + lc) * 64 + lq * 16);
        __builtin_amdgcn_s_setprio(1);
        #pragma unroll
        for (int mf = 0; mf < 4; ++mf)
            #pragma unroll
            for (int nf = 0; nf < 4; ++nf)
                acc[mf][nf] = mfma16(af[mf], bfr[nf], acc[mf][nf]);
        __builtin_amdgcn_s_setprio(0);
        __syncthreads();
    }
    #pragma unroll
    for (int mf = 0; mf < 4; ++mf) {
        #pragma unroll
        for (int nf = 0; nf < 4; ++nf) {
            int n = nbase + wc * 64 + nf * 16 + lc;
            float bv = bias[n];
            int m0 = mbase + wr * 64 + mf * 16 + lq * 4;
            if (MODE == 0) {
                int sect = n / 768, cc = n % 768;
                int h = cc >> 6, d = cc & 63;
                int b = m0 >> 11, t0 = m0 & 2047;
                long bh = (long)b * N_HEAD + h;
                if (sect == 0) {
                    #pragma unroll
                    for (int r = 0; r < 4; ++r)
                        qo[(bh * SEQ + t0 + r) * HD + d] = (bf16)((acc[mf][nf][r] + bv) * 0.18033688f);
                } else if (sect == 1) {
                    #pragma unroll
                    for (int r = 0; r < 4; ++r)
                        ko[(bh * SEQ + t0 + r) * HD + d] = (bf16)(acc[mf][nf][r] + bv);
                } else {
                    bf16x4 o;
                    #pragma unroll
                    for (int r = 0; r < 4; ++r) o[r] = (bf16)(acc[mf][nf][r] + bv);
                    *(bf16x4*)&vto[(bh * HD + d) * SEQ + t0] = o;
                }
            } else {
                #pragma unroll
                for (int r = 0; r < 4; ++r)
                    outf[(long)(m0 + r) * N + n] = acc[mf][nf][r] + bv;
            }
        }
    }
}

// ---------------- flash attention: 32x32 MFMA, in-reg softmax, KV-SPLIT + in-block merge ----------
// grid: (bh 0..47, tauR 0..31), tau = 31-tauR (heavy first). Block = ONE 64-row q-tile, 4 waves.
// Pair A (waves 0-1): KV tiles [0,h); pair B (waves 2-3): [h,nkt), h=nkt/2. Own LDS buffer per pair.
// End: B parks (m,l,y) in LDS (overlay), A merges online-softmax partials and writes.
__global__ __launch_bounds__(256, 5)
void attn_kernel(const bf16* __restrict__ qg, const bf16* __restrict__ kg,
                 const bf16* __restrict__ vtg, bf16* __restrict__ yg) {
    __shared__ __align__(16) bf16 KV[4][64 * 64];  // [2*wp+0]=K, [2*wp+1]=V ; 32 KB
    int tid = threadIdx.x;
    int wave = tid >> 6, lane = tid & 63;
    int q5 = lane & 31, h = lane >> 5;
    int bh = blockIdx.x;
    int tau = gridDim.y - 1 - blockIdx.y;   // heavy blocks first
    int b = bh / N_HEAD, hh = bh % N_HEAD;
    int rh = wave & 1, wp = wave >> 1;
    int nkt  = tau + 1;
    int half = nkt >> 1;
    int base = wp ? half : 0;
    int cnt  = wp ? nkt - half : half;
    int maxc = nkt - half;
    long koff = (long)bh * SEQ * HD;
    long voff = (long)bh * HD * SEQ;
    int qrow = tau * 64 + rh * 32 + q5;

    // Q B-frags (pre-scaled by 0.125*log2e): col q = lane&31, k(d) = s*16 + h*8 + 0..7
    bf16x8 qf[4];
    #pragma unroll
    for (int s = 0; s < 4; ++s)
        qf[s] = *(const bf16x8*)&qg[koff + (long)qrow * HD + s * 16 + h * 8];

    f32x16 y0 = {}, y1 = {};
    float m2 = -INFINITY, lsum = 0.f;

    // stage map (per pair, 2 waves): wave covers rows rh*32 + j*8 + (lane>>3), j=0..3
    int srow0 = rh * 32 + (lane >> 3);
    int scolsw = ((lane & 7) ^ (lane >> 3)) << 3;   // pre-swizzled source col (elems)
    int rsw = lane & 7;                              // read-side XOR on 16B-group index
    const char* KsC = (const char*)KV[2 * wp];
    const char* VsC = (const char*)KV[2 * wp + 1];

    for (int i = 0; i < maxc; ++i) {
        int tt = base + i;
        bool active = i < cnt;
        if (active) {   // stage K and V^T tile tt into this pair's buffers (8 gloads/wave)
            int k0 = tt * 64;
            char* KsB = (char*)KV[2 * wp]     + rh * 4096;
            char* VsB = (char*)KV[2 * wp + 1] + rh * 4096;
            #pragma unroll
            for (int j = 0; j < 4; ++j) {
                gload16(kg + koff + (long)(k0 + srow0 + j * 8) * HD + scolsw,  KsB + j * 1024);
                gload16(vtg + voff + (long)(srow0 + j * 8) * SEQ + k0 + scolsw, VsB + j * 1024);
            }
        }
        __syncthreads();
        if (active) {
            int k0 = tt * 64;
            // S^T = K·Q^T: lane holds S[key-rows][q=q5]; s0 keys k0+0..31, s1 keys k0+32..63
            f32x16 s0 = {}, s1 = {};
            __builtin_amdgcn_s_setprio(1);
            #pragma unroll
            for (int s = 0; s < 4; ++s) {
                bf16x8 kf0 = *(const bf16x8*)(KsC + q5 * 128        + (((s * 2 + h) ^ rsw) << 4));
                bf16x8 kf1 = *(const bf16x8*)(KsC + (32 + q5) * 128 + (((s * 2 + h) ^ rsw) << 4));
                s0 = mfma32(kf0, qf[s], s0);
                s1 = mfma32(kf1, qf[s], s1);
            }
            __builtin_amdgcn_s_setprio(0);
            if (tt == nkt - 1) {   // diagonal tile (always in pair B): causal mask
                #pragma unroll
                for (int r = 0; r < 16; ++r) {
                    int ka = k0 + (r & 3) + 8 * (r >> 2) + 4 * h;
                    if (ka > qrow)      s0[r] = -INFINITY;
                    if (ka + 32 > qrow) s1[r] = -INFINITY;
                }
            }
            float pmax = s0[0];
            #pragma unroll
            for (int r = 1; r < 16; ++r) pmax = fmaxf(pmax, s0[r]);
            #pragma unroll
            for (int r = 0; r < 16; ++r) pmax = fmaxf(pmax, s1[r]);
            pmax = fmaxf(pmax, __shfl_xor(pmax, 32));
            if (!__all(pmax <= m2 + 11.5f)) {   // defer-max (base-2 units)
                float mnew = fmaxf(m2, pmax);
                float sc = __builtin_amdgcn_exp2f(m2 - mnew);
                #pragma unroll
                for (int r = 0; r < 16; ++r) { y0[r] *= sc; y1[r] *= sc; }
                lsum *= sc;
                m2 = mnew;
            }
            float psum = 0.f;
            u32 d0a[4], d1a[4], d0b[4], d1b[4];
            #pragma unroll
            for (int m = 0; m < 4; ++m) {
                union { bf16x4 v; u32 w[2]; } pa, pb;
                #pragma unroll
                for (int rr = 0; rr < 4; ++rr) {
                    float p0 = __builtin_amdgcn_exp2f(s0[4 * m + rr] - m2);
                    float p1 = __builtin_amdgcn_exp2f(s1[4 * m + rr] - m2);
                    psum += p0 + p1;
                    pa.v[rr] = (bf16)p0; pb.v[rr] = (bf16)p1;
                }
                d0a[m] = pa.w[0]; d1a[m] = pa.w[1];
                d0b[m] = pb.w[0]; d1b[m] = pb.w[1];
            }
            psum += __shfl_xor(psum, 32);
            lsum += psum;
            u32 e0a[4], e1a[4], e0b[4], e1b[4];
            #pragma unroll
            for (int m = 0; m < 4; ++m) {
                e0a[m] = __shfl_xor(d0a[m], 32); e1a[m] = __shfl_xor(d1a[m], 32);
                e0b[m] = __shfl_xor(d0b[m], 32); e1b[m] = __shfl_xor(d1b[m], 32);
            }
            // Y^T += V^T·P^T: PV A-frag slot s needs keys s*16 + 8h + 0..7
            __builtin_amdgcn_s_setprio(1);
            #pragma unroll
            for (int s = 0; s < 4; ++s) {
                int m0 = 2 * (s & 1), m1 = m0 + 1;
                union { bf16x8 v; u32 w[4]; } fr;
                if (s < 2) {
                    fr.w[0] = h ? e0a[m1] : d0a[m0];
                    fr.w[1] = h ? e1a[m1] : d1a[m0];
                    fr.w[2] = h ? d0a[m1] : e0a[m0];
                    fr.w[3] = h ? d1a[m1] : e1a[m0];
                } else {
                    fr.w[0] = h ? e0b[m1] : d0b[m0];
                    fr.w[1] = h ? e1b[m1] : d1b[m0];
                    fr.w[2] = h ? d0b[m1] : e0b[m0];
                    fr.w[3] = h ? d1b[m1] : e1b[m0];
                }
                bf16x8 v0 = *(const bf16x8*)(VsC + q5 * 128        + (((s * 2 + h) ^ rsw) << 4));
                bf16x8 v1 = *(const bf16x8*)(VsC + (32 + q5) * 128 + (((s * 2 + h) ^ rsw) << 4));
                y0 = mfma32(v0, fr.v, y0);
                y1 = mfma32(v1, fr.v, y1);
            }
            __builtin_amdgcn_s_setprio(0);
        }
        __syncthreads();
    }

    // ----- merge partials: B parks in LDS (overlay on KV), A combines and writes -----
    float* ms = (float*)&KV[0][0];
    int slot = (rh * 64 + lane) * 36;   // {0:m, 1:l, 4..19:y0, 20..35:y1}, 16B-aligned
    if (wp) {
        ms[slot] = m2; ms[slot + 1] = lsum;
        #pragma unroll
        for (int r = 0; r < 16; ++r) { ms[slot + 4 + r] = y0[r]; ms[slot + 20 + r] = y1[r]; }
    }
    __syncthreads();
    if (!wp) {
        float mB = ms[slot], lB = ms[slot + 1];
        float mf = fmaxf(m2, mB);
        float a  = __builtin_amdgcn_exp2f(m2 - mf);
        float bb = __builtin_amdgcn_exp2f(mB - mf);
        float inv = 1.f / (lsum * a + lB * bb);
        long rowoff = ((long)b * SEQ + qrow) * D_MODEL + (long)hh * HD;
        #pragma unroll
        for (int m = 0; m < 4; ++m) {
            bf16x4 o0, o1;
            #pragma unroll
            for (int rr = 0; rr < 4; ++rr) {
                o0[rr] = (bf16)((y0[4 * m + rr] * a + ms[slot + 4 + 4 * m + rr] * bb) * inv);
                o1[rr] = (bf16)((y1[4 * m + rr] * a + ms[slot + 20 + 4 * m + rr] * bb) * inv);
            }
            *(bf16x4*)&yg[rowoff + 8 * m + 4 * h]      = o0;
            *(bf16x4*)&yg[rowoff + 32 + 8 * m + 4 * h] = o1;
        }
    }
}

extern "C" void kernel_launch(void* const* d_in, const int* in_sizes, int n_in,
                              void* d_out, int out_size, void* d_ws, size_t ws_size,
                              hipStream_t stream) {
    const float* x      = (const float*)d_in[0];
    const float* W_attn = (const float*)d_in[1];
    const float* b_attn = (const float*)d_in[2];
    const float* W_proj = (const float*)d_in[3];
    const float* b_proj = (const float*)d_in[4];
    float* out = (float*)d_out;

    char* ws = (char*)d_ws;
    size_t off = 0;
    auto alloc = [&](size_t bytes) { void* p = ws + off; off += (bytes + 255) & ~255ULL; return p; };
    bf16* xb  = (bf16*)alloc(8192ULL * 768 * 2);
    bf16* Wab = (bf16*)alloc(2304ULL * 768 * 2);
    bf16* Wpb = (bf16*)alloc(768ULL * 768 * 2);
    bf16* qb_ = (bf16*)alloc((size_t)BH * SEQ * HD * 2);
    bf16* kb_ = (bf16*)alloc((size_t)BH * SEQ * HD * 2);
    bf16* vtb = (bf16*)alloc((size_t)BH * SEQ * HD * 2);
    bf16* yb  = (bf16*)alloc(8192ULL * 768 * 2);

    hipLaunchKernelGGL(cvt_bf16, dim3((8192 * 768 / 4 + 255) / 256), dim3(256), 0, stream,
                       x, xb, 8192 * 768);
    hipLaunchKernelGGL(transpose_cvt, dim3(2304 / 64, 768 / 64), dim3(256), 0, stream,
                       W_attn, Wab, 768, 2304);
    hipLaunchKernelGGL(transpose_cvt, dim3(768 / 64, 768 / 64), dim3(256), 0, stream,
                       W_proj, Wpb, 768, 768);
    hipLaunchKernelGGL((gemm_bt<0>), dim3(64, 18), dim3(256), 0, stream,
                       xb, Wab, b_attn, qb_, kb_, vtb, (float*)nullptr, 8192, 2304, 768);
    hipLaunchKernelGGL(attn_kernel, dim3(48, 32), dim3(256), 0, stream,
                       qb_, kb_, vtb, yb);
    hipLaunchKernelGGL((gemm_bt<1>), dim3(64, 6), dim3(256), 0, stream,
                       yb, Wpb, b_proj, (bf16*)nullptr, (bf16*)nullptr, (bf16*)nullptr, out, 8192, 768, 768);
}

// Round 10
// 208.455 us; speedup vs baseline: 1.0768x; 1.0768x over previous
//
#include <hip/hip_runtime.h>
#include <hip/hip_bf16.h>
#include <math.h>

#define D_MODEL 768
#define N_HEAD  12
#define SEQ     2048
#define BATCH   4
#define HD      64
#define BH      (BATCH*N_HEAD)

typedef __bf16 bf16;
typedef __bf16 bf16x4 __attribute__((ext_vector_type(4)));
typedef __bf16 bf16x8 __attribute__((ext_vector_type(8)));
typedef float  f32x4  __attribute__((ext_vector_type(4)));
typedef float  f32x16 __attribute__((ext_vector_type(16)));
typedef unsigned int u32;

__device__ __forceinline__ f32x4 mfma16(bf16x8 a, bf16x8 b, f32x4 c) {
    return __builtin_amdgcn_mfma_f32_16x16x32_bf16(a, b, c, 0, 0, 0);
}
__device__ __forceinline__ f32x16 mfma32(bf16x8 a, bf16x8 b, f32x16 c) {
    return __builtin_amdgcn_mfma_f32_32x32x16_bf16(a, b, c, 0, 0, 0);
}

// async global->LDS, 16B per lane; LDS dest = wave-uniform base + lane*16
__device__ __forceinline__ void gload16(const void* g, void* l) {
    __builtin_amdgcn_global_load_lds((const __attribute__((address_space(1))) u32*)g,
                                     (__attribute__((address_space(3))) u32*)l, 16, 0, 0);
}

// ---------------- prep kernels ----------------
__global__ void cvt_bf16(const float* __restrict__ in, bf16* __restrict__ out, int n) {
    int i = (blockIdx.x * blockDim.x + threadIdx.x) * 4;
    if (i < n) {
        float4 v = *(const float4*)(in + i);
        bf16x4 o;
        o[0] = (bf16)v.x; o[1] = (bf16)v.y; o[2] = (bf16)v.z; o[3] = (bf16)v.w;
        *(bf16x4*)(out + i) = o;
    }
}

// in [R][C] fp32 -> out [C][R] bf16, LDS-tiled 64x64 (R,C multiples of 64)
__global__ __launch_bounds__(256)
void transpose_cvt(const float* __restrict__ in, bf16* __restrict__ out, int R, int C) {
    __shared__ float tile[64][65];
    int tid = threadIdx.x;
    int tr = blockIdx.y * 64, tc = blockIdx.x * 64;
    int r0 = tid >> 4, c0 = (tid & 15) * 4;
    #pragma unroll
    for (int i = 0; i < 4; ++i) {
        float4 v = *(const float4*)&in[(long)(tr + r0 + i * 16) * C + tc + c0];
        tile[r0 + i * 16][c0 + 0] = v.x;
        tile[r0 + i * 16][c0 + 1] = v.y;
        tile[r0 + i * 16][c0 + 2] = v.z;
        tile[r0 + i * 16][c0 + 3] = v.w;
    }
    __syncthreads();
    int orr = (tid & 15) * 4;
    #pragma unroll
    for (int i = 0; i < 4; ++i) {
        int oc = (tid >> 4) + i * 16;
        bf16x4 o;
        #pragma unroll
        for (int j = 0; j < 4; ++j) o[j] = (bf16)tile[orr + j][oc];
        *(bf16x4*)&out[(long)(tc + oc) * R + tr + orr] = o;
    }
}

// ---------------- GEMM (m97 structure): C = A[M,K] * Bt[N,K]^T + bias ----------------
// MODE 0: QKV epilogue (q pre-scaled by 0.125*log2e; scatter q/k row-major, v transposed), MODE 1: fp32 out
template<int MODE>
__global__ __launch_bounds__(256)
void gemm_bt(const bf16* __restrict__ A, const bf16* __restrict__ Bt,
             const float* __restrict__ bias,
             bf16* __restrict__ qo, bf16* __restrict__ ko, bf16* __restrict__ vto,
             float* __restrict__ outf,
             int M, int N, int K) {
    __shared__ bf16 As[128 * 32];   // linear, row stride 32 el (64B)
    __shared__ bf16 Bs[128 * 32];
    int tid = threadIdx.x;
    int wave = tid >> 6, lane = tid & 63;
    int wr = wave >> 1, wc = wave & 1;
    int lq = lane >> 4, lc = lane & 15;
    int mbase = blockIdx.x * 128, nbase = blockIdx.y * 128;
    int srow = wave * 32 + (lane >> 2), scol = (lane & 3) * 8;
    const bf16* aS = A  + (long)(mbase + srow) * K + scol;
    const bf16* bS = Bt + (long)(nbase + srow) * K + scol;
    char* AsB = (char*)As + wave * 2048;
    char* BsB = (char*)Bs + wave * 2048;
    f32x4 acc[4][4] = {};
    for (int kt = 0; kt < K; kt += 32) {
        gload16(aS + kt,                AsB);
        gload16(aS + 16 * (long)K + kt, AsB + 1024);
        gload16(bS + kt,                BsB);
        gload16(bS + 16 * (long)K + kt, BsB + 1024);
        __syncthreads();
        bf16x8 af[4], bfr[4];
        #pragma unroll
        for (int mf = 0; mf < 4; ++mf)
            af[mf]  = *(const bf16x8*)((char*)As + (wr * 64 + mf * 16 + lc) * 64 + lq * 16);
        #pragma unroll
        for (int nf = 0; nf < 4; ++nf)
            bfr[nf] = *(const bf16x8*)((char*)Bs + (wc * 64 + nf * 16 + lc) * 64 + lq * 16);
        __builtin_amdgcn_s_setprio(1);
        #pragma unroll
        for (int mf = 0; mf < 4; ++mf)
            #pragma unroll
            for (int nf = 0; nf < 4; ++nf)
                acc[mf][nf] = mfma16(af[mf], bfr[nf], acc[mf][nf]);
        __builtin_amdgcn_s_setprio(0);
        __syncthreads();
    }
    #pragma unroll
    for (int mf = 0; mf < 4; ++mf) {
        #pragma unroll
        for (int nf = 0; nf < 4; ++nf) {
            int n = nbase + wc * 64 + nf * 16 + lc;
            float bv = bias[n];
            int m0 = mbase + wr * 64 + mf * 16 + lq * 4;
            if (MODE == 0) {
                int sect = n / 768, cc = n % 768;
                int h = cc >> 6, d = cc & 63;
                int b = m0 >> 11, t0 = m0 & 2047;
                long bh = (long)b * N_HEAD + h;
                if (sect == 0) {
                    #pragma unroll
                    for (int r = 0; r < 4; ++r)
                        qo[(bh * SEQ + t0 + r) * HD + d] = (bf16)((acc[mf][nf][r] + bv) * 0.18033688f);
                } else if (sect == 1) {
                    #pragma unroll
                    for (int r = 0; r < 4; ++r)
                        ko[(bh * SEQ + t0 + r) * HD + d] = (bf16)(acc[mf][nf][r] + bv);
                } else {
                    bf16x4 o;
                    #pragma unroll
                    for (int r = 0; r < 4; ++r) o[r] = (bf16)(acc[mf][nf][r] + bv);
                    *(bf16x4*)&vto[(bh * HD + d) * SEQ + t0] = o;
                }
            } else {
                #pragma unroll
                for (int r = 0; r < 4; ++r)
                    outf[(long)(m0 + r) * N + n] = acc[mf][nf][r] + bv;
            }
        }
    }
}

// ---------------- flash attention: 32x32 MFMA, in-reg softmax, KV-SPLIT + in-block merge ----------
// grid: (bh 0..47, tauR 0..31), tau = 31-tauR (heavy first). Block = ONE 64-row q-tile, 4 waves.
// Pair A (waves 0-1): KV tiles [0,h); pair B (waves 2-3): [h,nkt), h=nkt/2. Own LDS buffer per pair.
// End: B parks (m,l,y) in LDS (overlay), A merges online-softmax partials and writes.
// launch_bounds (256,4): VGPR cap 128 -> no spill (r9's (256,5) cap forced spills: FETCH/WRITE 3x).
__global__ __launch_bounds__(256, 4)
void attn_kernel(const bf16* __restrict__ qg, const bf16* __restrict__ kg,
                 const bf16* __restrict__ vtg, bf16* __restrict__ yg) {
    __shared__ __align__(16) bf16 KV[4][64 * 64];  // [2*wp+0]=K, [2*wp+1]=V ; 32 KB
    int tid = threadIdx.x;
    int wave = tid >> 6, lane = tid & 63;
    int q5 = lane & 31, h = lane >> 5;
    int bh = blockIdx.x;
    int tau = gridDim.y - 1 - blockIdx.y;   // heavy blocks first
    int b = bh / N_HEAD, hh = bh % N_HEAD;
    int rh = wave & 1, wp = wave >> 1;
    int nkt  = tau + 1;
    int half = nkt >> 1;
    int base = wp ? half : 0;
    int cnt  = wp ? nkt - half : half;
    int maxc = nkt - half;
    long koff = (long)bh * SEQ * HD;
    long voff = (long)bh * HD * SEQ;
    int qrow = tau * 64 + rh * 32 + q5;

    // Q B-frags (pre-scaled by 0.125*log2e): col q = lane&31, k(d) = s*16 + h*8 + 0..7
    bf16x8 qf[4];
    #pragma unroll
    for (int s = 0; s < 4; ++s)
        qf[s] = *(const bf16x8*)&qg[koff + (long)qrow * HD + s * 16 + h * 8];

    f32x16 y0 = {}, y1 = {};
    float m2 = -INFINITY, lsum = 0.f;

    // stage map (per pair, 2 waves): wave covers rows rh*32 + j*8 + (lane>>3), j=0..3
    int srow0 = rh * 32 + (lane >> 3);
    int scolsw = ((lane & 7) ^ (lane >> 3)) << 3;   // pre-swizzled source col (elems)
    int rsw = lane & 7;                              // read-side XOR on 16B-group index
    const char* KsC = (const char*)KV[2 * wp];
    const char* VsC = (const char*)KV[2 * wp + 1];

    for (int i = 0; i < maxc; ++i) {
        int tt = base + i;
        bool active = i < cnt;
        if (active) {   // stage K and V^T tile tt into this pair's buffers (8 gloads/wave)
            int k0 = tt * 64;
            char* KsB = (char*)KV[2 * wp]     + rh * 4096;
            char* VsB = (char*)KV[2 * wp + 1] + rh * 4096;
            #pragma unroll
            for (int j = 0; j < 4; ++j) {
                gload16(kg + koff + (long)(k0 + srow0 + j * 8) * HD + scolsw,  KsB + j * 1024);
                gload16(vtg + voff + (long)(srow0 + j * 8) * SEQ + k0 + scolsw, VsB + j * 1024);
            }
        }
        __syncthreads();
        if (active) {
            int k0 = tt * 64;
            // S^T = K·Q^T: lane holds S[key-rows][q=q5]; s0 keys k0+0..31, s1 keys k0+32..63
            f32x16 s0 = {}, s1 = {};
            __builtin_amdgcn_s_setprio(1);
            #pragma unroll
            for (int s = 0; s < 4; ++s) {
                bf16x8 kf0 = *(const bf16x8*)(KsC + q5 * 128        + (((s * 2 + h) ^ rsw) << 4));
                bf16x8 kf1 = *(const bf16x8*)(KsC + (32 + q5) * 128 + (((s * 2 + h) ^ rsw) << 4));
                s0 = mfma32(kf0, qf[s], s0);
                s1 = mfma32(kf1, qf[s], s1);
            }
            __builtin_amdgcn_s_setprio(0);
            if (tt == nkt - 1) {   // diagonal tile (always in pair B): causal mask
                #pragma unroll
                for (int r = 0; r < 16; ++r) {
                    int ka = k0 + (r & 3) + 8 * (r >> 2) + 4 * h;
                    if (ka > qrow)      s0[r] = -INFINITY;
                    if (ka + 32 > qrow) s1[r] = -INFINITY;
                }
            }
            float pmax = s0[0];
            #pragma unroll
            for (int r = 1; r < 16; ++r) pmax = fmaxf(pmax, s0[r]);
            #pragma unroll
            for (int r = 0; r < 16; ++r) pmax = fmaxf(pmax, s1[r]);
            pmax = fmaxf(pmax, __shfl_xor(pmax, 32));
            if (!__all(pmax <= m2 + 11.5f)) {   // defer-max (base-2 units)
                float mnew = fmaxf(m2, pmax);
                float sc = __builtin_amdgcn_exp2f(m2 - mnew);
                #pragma unroll
                for (int r = 0; r < 16; ++r) { y0[r] *= sc; y1[r] *= sc; }
                lsum *= sc;
                m2 = mnew;
            }
            float psum = 0.f;
            u32 d0a[4], d1a[4], d0b[4], d1b[4];
            #pragma unroll
            for (int m = 0; m < 4; ++m) {
                union { bf16x4 v; u32 w[2]; } pa, pb;
                #pragma unroll
                for (int rr = 0; rr < 4; ++rr) {
                    float p0 = __builtin_amdgcn_exp2f(s0[4 * m + rr] - m2);
                    float p1 = __builtin_amdgcn_exp2f(s1[4 * m + rr] - m2);
                    psum += p0 + p1;
                    pa.v[rr] = (bf16)p0; pb.v[rr] = (bf16)p1;
                }
                d0a[m] = pa.w[0]; d1a[m] = pa.w[1];
                d0b[m] = pb.w[0]; d1b[m] = pb.w[1];
            }
            psum += __shfl_xor(psum, 32);
            lsum += psum;
            u32 e0a[4], e1a[4], e0b[4], e1b[4];
            #pragma unroll
            for (int m = 0; m < 4; ++m) {
                e0a[m] = __shfl_xor(d0a[m], 32); e1a[m] = __shfl_xor(d1a[m], 32);
                e0b[m] = __shfl_xor(d0b[m], 32); e1b[m] = __shfl_xor(d1b[m], 32);
            }
            // Y^T += V^T·P^T: PV A-frag slot s needs keys s*16 + 8h + 0..7
            __builtin_amdgcn_s_setprio(1);
            #pragma unroll
            for (int s = 0; s < 4; ++s) {
                int m0 = 2 * (s & 1), m1 = m0 + 1;
                union { bf16x8 v; u32 w[4]; } fr;
                if (s < 2) {
                    fr.w[0] = h ? e0a[m1] : d0a[m0];
                    fr.w[1] = h ? e1a[m1] : d1a[m0];
                    fr.w[2] = h ? d0a[m1] : e0a[m0];
                    fr.w[3] = h ? d1a[m1] : e1a[m0];
                } else {
                    fr.w[0] = h ? e0b[m1] : d0b[m0];
                    fr.w[1] = h ? e1b[m1] : d1b[m0];
                    fr.w[2] = h ? d0b[m1] : e0b[m0];
                    fr.w[3] = h ? d1b[m1] : e1b[m0];
                }
                bf16x8 v0 = *(const bf16x8*)(VsC + q5 * 128        + (((s * 2 + h) ^ rsw) << 4));
                bf16x8 v1 = *(const bf16x8*)(VsC + (32 + q5) * 128 + (((s * 2 + h) ^ rsw) << 4));
                y0 = mfma32(v0, fr.v, y0);
                y1 = mfma32(v1, fr.v, y1);
            }
            __builtin_amdgcn_s_setprio(0);
        }
        __syncthreads();
    }

    // ----- merge partials: B parks in LDS (overlay on KV), A combines and writes -----
    float* ms = (float*)&KV[0][0];
    int slot = (rh * 64 + lane) * 36;   // {0:m, 1:l, 4..19:y0, 20..35:y1}, 16B-aligned
    if (wp) {
        ms[slot] = m2; ms[slot + 1] = lsum;
        #pragma unroll
        for (int r = 0; r < 16; ++r) { ms[slot + 4 + r] = y0[r]; ms[slot + 20 + r] = y1[r]; }
    }
    __syncthreads();
    if (!wp) {
        float mB = ms[slot], lB = ms[slot + 1];
        float mf = fmaxf(m2, mB);
        float a  = __builtin_amdgcn_exp2f(m2 - mf);
        float bb = __builtin_amdgcn_exp2f(mB - mf);
        float inv = 1.f / (lsum * a + lB * bb);
        long rowoff = ((long)b * SEQ + qrow) * D_MODEL + (long)hh * HD;
        #pragma unroll
        for (int m = 0; m < 4; ++m) {
            bf16x4 o0, o1;
            #pragma unroll
            for (int rr = 0; rr < 4; ++rr) {
                o0[rr] = (bf16)((y0[4 * m + rr] * a + ms[slot + 4 + 4 * m + rr] * bb) * inv);
                o1[rr] = (bf16)((y1[4 * m + rr] * a + ms[slot + 20 + 4 * m + rr] * bb) * inv);
            }
            *(bf16x4*)&yg[rowoff + 8 * m + 4 * h]      = o0;
            *(bf16x4*)&yg[rowoff + 32 + 8 * m + 4 * h] = o1;
        }
    }
}

extern "C" void kernel_launch(void* const* d_in, const int* in_sizes, int n_in,
                              void* d_out, int out_size, void* d_ws, size_t ws_size,
                              hipStream_t stream) {
    const float* x      = (const float*)d_in[0];
    const float* W_attn = (const float*)d_in[1];
    const float* b_attn = (const float*)d_in[2];
    const float* W_proj = (const float*)d_in[3];
    const float* b_proj = (const float*)d_in[4];
    float* out = (float*)d_out;

    char* ws = (char*)d_ws;
    size_t off = 0;
    auto alloc = [&](size_t bytes) { void* p = ws + off; off += (bytes + 255) & ~255ULL; return p; };
    bf16* xb  = (bf16*)alloc(8192ULL * 768 * 2);
    bf16* Wab = (bf16*)alloc(2304ULL * 768 * 2);
    bf16* Wpb = (bf16*)alloc(768ULL * 768 * 2);
    bf16* qb_ = (bf16*)alloc((size_t)BH * SEQ * HD * 2);
    bf16* kb_ = (bf16*)alloc((size_t)BH * SEQ * HD * 2);
    bf16* vtb = (bf16*)alloc((size_t)BH * SEQ * HD * 2);
    bf16* yb  = (bf16*)alloc(8192ULL * 768 * 2);

    hipLaunchKernelGGL(cvt_bf16, dim3((8192 * 768 / 4 + 255) / 256), dim3(256), 0, stream,
                       x, xb, 8192 * 768);
    hipLaunchKernelGGL(transpose_cvt, dim3(2304 / 64, 768 / 64), dim3(256), 0, stream,
                       W_attn, Wab, 768, 2304);
    hipLaunchKernelGGL(transpose_cvt, dim3(768 / 64, 768 / 64), dim3(256), 0, stream,
                       W_proj, Wpb, 768, 768);
    hipLaunchKernelGGL((gemm_bt<0>), dim3(64, 18), dim3(256), 0, stream,
                       xb, Wab, b_attn, qb_, kb_, vtb, (float*)nullptr, 8192, 2304, 768);
    hipLaunchKernelGGL(attn_kernel, dim3(48, 32), dim3(256), 0, stream,
                       qb_, kb_, vtb, yb);
    hipLaunchKernelGGL((gemm_bt<1>), dim3(64, 6), dim3(256), 0, stream,
                       yb, Wpb, b_proj, (bf16*)nullptr, (bf16*)nullptr, (bf16*)nullptr, out, 8192, 768, 768);
}

// Round 11
// 191.699 us; speedup vs baseline: 1.1710x; 1.0874x over previous
//
#include <hip/hip_runtime.h>
#include <hip/hip_bf16.h>
#include <math.h>

#define D_MODEL 768
#define N_HEAD  12
#define SEQ     2048
#define BATCH   4
#define HD      64
#define BH      (BATCH*N_HEAD)

typedef __bf16 bf16;
typedef __bf16 bf16x4 __attribute__((ext_vector_type(4)));
typedef __bf16 bf16x8 __attribute__((ext_vector_type(8)));
typedef float  f32x4  __attribute__((ext_vector_type(4)));
typedef float  f32x16 __attribute__((ext_vector_type(16)));
typedef unsigned int u32;

__device__ __forceinline__ f32x4 mfma16(bf16x8 a, bf16x8 b, f32x4 c) {
    return __builtin_amdgcn_mfma_f32_16x16x32_bf16(a, b, c, 0, 0, 0);
}
__device__ __forceinline__ f32x16 mfma32(bf16x8 a, bf16x8 b, f32x16 c) {
    return __builtin_amdgcn_mfma_f32_32x32x16_bf16(a, b, c, 0, 0, 0);
}

// async global->LDS, 16B per lane; LDS dest = wave-uniform base + lane*16
__device__ __forceinline__ void gload16(const void* g, void* l) {
    __builtin_amdgcn_global_load_lds((const __attribute__((address_space(1))) u32*)g,
                                     (__attribute__((address_space(3))) u32*)l, 16, 0, 0);
}

// ---------------- fused prep kernel ----------------
// blocks [0,6144): cvt x fp32->bf16 (1024 elems/block)
// blocks [6144,6576): transpose W_attn 64x64 tiles (36x12)
// blocks [6576,6720): transpose W_proj tiles (12x12)
__global__ __launch_bounds__(256)
void prep(const float* __restrict__ x, const float* __restrict__ Wa, const float* __restrict__ Wp,
          bf16* __restrict__ xb, bf16* __restrict__ Wab, bf16* __restrict__ Wpb) {
    __shared__ float tile[64][65];
    int blk = blockIdx.x, tid = threadIdx.x;
    if (blk < 6144) {
        int i = (blk * 256 + tid) * 4;
        float4 v = *(const float4*)(x + i);
        bf16x4 o;
        o[0] = (bf16)v.x; o[1] = (bf16)v.y; o[2] = (bf16)v.z; o[3] = (bf16)v.w;
        *(bf16x4*)(xb + i) = o;
        return;
    }
    const float* in; bf16* out; int C; int tile_id;
    if (blk < 6576) { in = Wa; out = Wab; C = 2304; tile_id = blk - 6144; }
    else            { in = Wp; out = Wpb; C = 768;  tile_id = blk - 6576; }
    const int R = 768;
    int tpr = C / 64;
    int tr = (tile_id / tpr) * 64, tc = (tile_id % tpr) * 64;
    int r0 = tid >> 4, c0 = (tid & 15) * 4;
    #pragma unroll
    for (int i = 0; i < 4; ++i) {
        float4 v = *(const float4*)&in[(long)(tr + r0 + i * 16) * C + tc + c0];
        tile[r0 + i * 16][c0 + 0] = v.x;
        tile[r0 + i * 16][c0 + 1] = v.y;
        tile[r0 + i * 16][c0 + 2] = v.z;
        tile[r0 + i * 16][c0 + 3] = v.w;
    }
    __syncthreads();
    int orr = (tid & 15) * 4;
    #pragma unroll
    for (int i = 0; i < 4; ++i) {
        int oc = (tid >> 4) + i * 16;
        bf16x4 o;
        #pragma unroll
        for (int j = 0; j < 4; ++j) o[j] = (bf16)tile[orr + j][oc];
        *(bf16x4*)&out[(long)(tc + oc) * R + tr + orr] = o;
    }
}

// ---------------- GEMM: BK=64, both-sides XOR swizzle. C = A[M,K]*Bt[N,K]^T + bias --------------
// MODE 0: QKV epilogue (q pre-scaled by 0.125*log2e; scatter q/k row-major, v transposed), MODE 1: fp32 out
// LDS[row][g16] holds global[row][g16 ^ (row&7)] (row stride 128B = 8 x 16B groups);
// staged via linear gload16 dest + pre-swizzled source col; reads XOR with (row&7) -> ~2-way conflicts.
template<int MODE>
__global__ __launch_bounds__(256)
void gemm_bt(const bf16* __restrict__ A, const bf16* __restrict__ Bt,
             const float* __restrict__ bias,
             bf16* __restrict__ qo, bf16* __restrict__ ko, bf16* __restrict__ vto,
             float* __restrict__ outf,
             int M, int N, int K) {
    __shared__ bf16 As[128 * 64];
    __shared__ bf16 Bs[128 * 64];
    int tid = threadIdx.x;
    int wave = tid >> 6, lane = tid & 63;
    int wr = wave >> 1, wc = wave & 1;
    int lq = lane >> 4, lc = lane & 15;
    int mbase = blockIdx.x * 128, nbase = blockIdx.y * 128;
    // staging: wave w instr j covers rows w*32 + j*8 + (lane>>3), src 16B-group (lane&7)^(lane>>3)
    int srow = wave * 32 + (lane >> 3);
    int scol = ((lane & 7) ^ (lane >> 3)) << 3;   // elems
    const bf16* aS = A  + (long)(mbase + srow) * K + scol;
    const bf16* bS = Bt + (long)(nbase + srow) * K + scol;
    char* AsB = (char*)As + wave * 4096;
    char* BsB = (char*)Bs + wave * 4096;
    f32x4 acc[4][4] = {};
    for (int kt = 0; kt < K; kt += 64) {
        #pragma unroll
        for (int j = 0; j < 4; ++j) {
            gload16(aS + kt + (long)j * 8 * K, AsB + j * 1024);
            gload16(bS + kt + (long)j * 8 * K, BsB + j * 1024);
        }
        __syncthreads();
        #pragma unroll
        for (int ksub = 0; ksub < 2; ++ksub) {
            bf16x8 af[4], bfr[4];
            #pragma unroll
            for (int mf = 0; mf < 4; ++mf) {
                int R = wr * 64 + mf * 16 + lc;
                af[mf]  = *(const bf16x8*)((char*)As + R * 128 + (((ksub * 4 + lq) ^ (lc & 7)) << 4));
            }
            #pragma unroll
            for (int nf = 0; nf < 4; ++nf) {
                int R = wc * 64 + nf * 16 + lc;
                bfr[nf] = *(const bf16x8*)((char*)Bs + R * 128 + (((ksub * 4 + lq) ^ (lc & 7)) << 4));
            }
            __builtin_amdgcn_s_setprio(1);
            #pragma unroll
            for (int mf = 0; mf < 4; ++mf)
                #pragma unroll
                for (int nf = 0; nf < 4; ++nf)
                    acc[mf][nf] = mfma16(af[mf], bfr[nf], acc[mf][nf]);
            __builtin_amdgcn_s_setprio(0);
        }
        __syncthreads();
    }
    #pragma unroll
    for (int mf = 0; mf < 4; ++mf) {
        #pragma unroll
        for (int nf = 0; nf < 4; ++nf) {
            int n = nbase + wc * 64 + nf * 16 + lc;
            float bv = bias[n];
            int m0 = mbase + wr * 64 + mf * 16 + lq * 4;
            if (MODE == 0) {
                int sect = n / 768, cc = n % 768;
                int h = cc >> 6, d = cc & 63;
                int b = m0 >> 11, t0 = m0 & 2047;
                long bh = (long)b * N_HEAD + h;
                if (sect == 0) {
                    #pragma unroll
                    for (int r = 0; r < 4; ++r)
                        qo[(bh * SEQ + t0 + r) * HD + d] = (bf16)((acc[mf][nf][r] + bv) * 0.18033688f);
                } else if (sect == 1) {
                    #pragma unroll
                    for (int r = 0; r < 4; ++r)
                        ko[(bh * SEQ + t0 + r) * HD + d] = (bf16)(acc[mf][nf][r] + bv);
                } else {
                    bf16x4 o;
                    #pragma unroll
                    for (int r = 0; r < 4; ++r) o[r] = (bf16)(acc[mf][nf][r] + bv);
                    *(bf16x4*)&vto[(bh * HD + d) * SEQ + t0] = o;
                }
            } else {
                #pragma unroll
                for (int r = 0; r < 4; ++r)
                    outf[(long)(m0 + r) * N + n] = acc[mf][nf][r] + bv;
            }
        }
    }
}

// ---------------- flash attention: 32x32 MFMA, in-reg softmax, KV-SPLIT + in-block merge ----------
// grid: (bh 0..47, tauR 0..31), tau = 31-tauR (heavy first). Block = ONE 64-row q-tile, 4 waves.
// Pair A (waves 0-1): KV tiles [0,h); pair B (waves 2-3): [h,nkt). B parks partials in LDS, A merges.
// launch_bounds (256,4): VGPR cap 128 -> no spill (r9's (256,5) forced spills).
__global__ __launch_bounds__(256, 4)
void attn_kernel(const bf16* __restrict__ qg, const bf16* __restrict__ kg,
                 const bf16* __restrict__ vtg, bf16* __restrict__ yg) {
    __shared__ __align__(16) bf16 KV[4][64 * 64];  // [2*wp+0]=K, [2*wp+1]=V ; 32 KB
    int tid = threadIdx.x;
    int wave = tid >> 6, lane = tid & 63;
    int q5 = lane & 31, h = lane >> 5;
    int bh = blockIdx.x;
    int tau = gridDim.y - 1 - blockIdx.y;   // heavy blocks first
    int b = bh / N_HEAD, hh = bh % N_HEAD;
    int rh = wave & 1, wp = wave >> 1;
    int nkt  = tau + 1;
    int half = nkt >> 1;
    int base = wp ? half : 0;
    int cnt  = wp ? nkt - half : half;
    int maxc = nkt - half;
    long koff = (long)bh * SEQ * HD;
    long voff = (long)bh * HD * SEQ;
    int qrow = tau * 64 + rh * 32 + q5;

    bf16x8 qf[4];
    #pragma unroll
    for (int s = 0; s < 4; ++s)
        qf[s] = *(const bf16x8*)&qg[koff + (long)qrow * HD + s * 16 + h * 8];

    f32x16 y0 = {}, y1 = {};
    float m2 = -INFINITY, lsum = 0.f;

    int srow0 = rh * 32 + (lane >> 3);
    int scolsw = ((lane & 7) ^ (lane >> 3)) << 3;
    int rsw = lane & 7;
    const char* KsC = (const char*)KV[2 * wp];
    const char* VsC = (const char*)KV[2 * wp + 1];

    for (int i = 0; i < maxc; ++i) {
        int tt = base + i;
        bool active = i < cnt;
        if (active) {
            int k0 = tt * 64;
            char* KsB = (char*)KV[2 * wp]     + rh * 4096;
            char* VsB = (char*)KV[2 * wp + 1] + rh * 4096;
            #pragma unroll
            for (int j = 0; j < 4; ++j) {
                gload16(kg + koff + (long)(k0 + srow0 + j * 8) * HD + scolsw,  KsB + j * 1024);
                gload16(vtg + voff + (long)(srow0 + j * 8) * SEQ + k0 + scolsw, VsB + j * 1024);
            }
        }
        __syncthreads();
        if (active) {
            int k0 = tt * 64;
            f32x16 s0 = {}, s1 = {};
            __builtin_amdgcn_s_setprio(1);
            #pragma unroll
            for (int s = 0; s < 4; ++s) {
                bf16x8 kf0 = *(const bf16x8*)(KsC + q5 * 128        + (((s * 2 + h) ^ rsw) << 4));
                bf16x8 kf1 = *(const bf16x8*)(KsC + (32 + q5) * 128 + (((s * 2 + h) ^ rsw) << 4));
                s0 = mfma32(kf0, qf[s], s0);
                s1 = mfma32(kf1, qf[s], s1);
            }
            __builtin_amdgcn_s_setprio(0);
            if (tt == nkt - 1) {
                #pragma unroll
                for (int r = 0; r < 16; ++r) {
                    int ka = k0 + (r & 3) + 8 * (r >> 2) + 4 * h;
                    if (ka > qrow)      s0[r] = -INFINITY;
                    if (ka + 32 > qrow) s1[r] = -INFINITY;
                }
            }
            float pmax = s0[0];
            #pragma unroll
            for (int r = 1; r < 16; ++r) pmax = fmaxf(pmax, s0[r]);
            #pragma unroll
            for (int r = 0; r < 16; ++r) pmax = fmaxf(pmax, s1[r]);
            pmax = fmaxf(pmax, __shfl_xor(pmax, 32));
            if (!__all(pmax <= m2 + 11.5f)) {
                float mnew = fmaxf(m2, pmax);
                float sc = __builtin_amdgcn_exp2f(m2 - mnew);
                #pragma unroll
                for (int r = 0; r < 16; ++r) { y0[r] *= sc; y1[r] *= sc; }
                lsum *= sc;
                m2 = mnew;
            }
            float psum = 0.f;
            u32 d0a[4], d1a[4], d0b[4], d1b[4];
            #pragma unroll
            for (int m = 0; m < 4; ++m) {
                union { bf16x4 v; u32 w[2]; } pa, pb;
                #pragma unroll
                for (int rr = 0; rr < 4; ++rr) {
                    float p0 = __builtin_amdgcn_exp2f(s0[4 * m + rr] - m2);
                    float p1 = __builtin_amdgcn_exp2f(s1[4 * m + rr] - m2);
                    psum += p0 + p1;
                    pa.v[rr] = (bf16)p0; pb.v[rr] = (bf16)p1;
                }
                d0a[m] = pa.w[0]; d1a[m] = pa.w[1];
                d0b[m] = pb.w[0]; d1b[m] = pb.w[1];
            }
            psum += __shfl_xor(psum, 32);
            lsum += psum;
            u32 e0a[4], e1a[4], e0b[4], e1b[4];
            #pragma unroll
            for (int m = 0; m < 4; ++m) {
                e0a[m] = __shfl_xor(d0a[m], 32); e1a[m] = __shfl_xor(d1a[m], 32);
                e0b[m] = __shfl_xor(d0b[m], 32); e1b[m] = __shfl_xor(d1b[m], 32);
            }
            __builtin_amdgcn_s_setprio(1);
            #pragma unroll
            for (int s = 0; s < 4; ++s) {
                int m0 = 2 * (s & 1), m1 = m0 + 1;
                union { bf16x8 v; u32 w[4]; } fr;
                if (s < 2) {
                    fr.w[0] = h ? e0a[m1] : d0a[m0];
                    fr.w[1] = h ? e1a[m1] : d1a[m0];
                    fr.w[2] = h ? d0a[m1] : e0a[m0];
                    fr.w[3] = h ? d1a[m1] : e1a[m0];
                } else {
                    fr.w[0] = h ? e0b[m1] : d0b[m0];
                    fr.w[1] = h ? e1b[m1] : d1b[m0];
                    fr.w[2] = h ? d0b[m1] : e0b[m0];
                    fr.w[3] = h ? d1b[m1] : e1b[m0];
                }
                bf16x8 v0 = *(const bf16x8*)(VsC + q5 * 128        + (((s * 2 + h) ^ rsw) << 4));
                bf16x8 v1 = *(const bf16x8*)(VsC + (32 + q5) * 128 + (((s * 2 + h) ^ rsw) << 4));
                y0 = mfma32(v0, fr.v, y0);
                y1 = mfma32(v1, fr.v, y1);
            }
            __builtin_amdgcn_s_setprio(0);
        }
        __syncthreads();
    }

    float* ms = (float*)&KV[0][0];
    int slot = (rh * 64 + lane) * 36;
    if (wp) {
        ms[slot] = m2; ms[slot + 1] = lsum;
        #pragma unroll
        for (int r = 0; r < 16; ++r) { ms[slot + 4 + r] = y0[r]; ms[slot + 20 + r] = y1[r]; }
    }
    __syncthreads();
    if (!wp) {
        float mB = ms[slot], lB = ms[slot + 1];
        float mf = fmaxf(m2, mB);
        float a  = __builtin_amdgcn_exp2f(m2 - mf);
        float bb = __builtin_amdgcn_exp2f(mB - mf);
        float inv = 1.f / (lsum * a + lB * bb);
        long rowoff = ((long)b * SEQ + qrow) * D_MODEL + (long)hh * HD;
        #pragma unroll
        for (int m = 0; m < 4; ++m) {
            bf16x4 o0, o1;
            #pragma unroll
            for (int rr = 0; rr < 4; ++rr) {
                o0[rr] = (bf16)((y0[4 * m + rr] * a + ms[slot + 4 + 4 * m + rr] * bb) * inv);
                o1[rr] = (bf16)((y1[4 * m + rr] * a + ms[slot + 20 + 4 * m + rr] * bb) * inv);
            }
            *(bf16x4*)&yg[rowoff + 8 * m + 4 * h]      = o0;
            *(bf16x4*)&yg[rowoff + 32 + 8 * m + 4 * h] = o1;
        }
    }
}

extern "C" void kernel_launch(void* const* d_in, const int* in_sizes, int n_in,
                              void* d_out, int out_size, void* d_ws, size_t ws_size,
                              hipStream_t stream) {
    const float* x      = (const float*)d_in[0];
    const float* W_attn = (const float*)d_in[1];
    const float* b_attn = (const float*)d_in[2];
    const float* W_proj = (const float*)d_in[3];
    const float* b_proj = (const float*)d_in[4];
    float* out = (float*)d_out;

    char* ws = (char*)d_ws;
    size_t off = 0;
    auto alloc = [&](size_t bytes) { void* p = ws + off; off += (bytes + 255) & ~255ULL; return p; };
    bf16* xb  = (bf16*)alloc(8192ULL * 768 * 2);
    bf16* Wab = (bf16*)alloc(2304ULL * 768 * 2);
    bf16* Wpb = (bf16*)alloc(768ULL * 768 * 2);
    bf16* qb_ = (bf16*)alloc((size_t)BH * SEQ * HD * 2);
    bf16* kb_ = (bf16*)alloc((size_t)BH * SEQ * HD * 2);
    bf16* vtb = (bf16*)alloc((size_t)BH * SEQ * HD * 2);
    bf16* yb  = (bf16*)alloc(8192ULL * 768 * 2);

    hipLaunchKernelGGL(prep, dim3(6720), dim3(256), 0, stream,
                       x, W_attn, W_proj, xb, Wab, Wpb);
    hipLaunchKernelGGL((gemm_bt<0>), dim3(64, 18), dim3(256), 0, stream,
                       xb, Wab, b_attn, qb_, kb_, vtb, (float*)nullptr, 8192, 2304, 768);
    hipLaunchKernelGGL(attn_kernel, dim3(48, 32), dim3(256), 0, stream,
                       qb_, kb_, vtb, yb);
    hipLaunchKernelGGL((gemm_bt<1>), dim3(64, 6), dim3(256), 0, stream,
                       yb, Wpb, b_proj, (bf16*)nullptr, (bf16*)nullptr, (bf16*)nullptr, out, 8192, 768, 768);
}